// Round 5
// baseline (390.665 us; speedup 1.0000x reference)
//
#include <hip/hip_runtime.h>

// MeanPooling: segment mean over sorted int32 segment ids (confirmed int32 by r3 pass).
//   N = 2^25 float32, NUM_SEGMENTS = 100000, index sorted ascending.
// Fused single-kernel design: one 64-lane wave per segment.
//   - lanes 0..1 binary-search lower_bound(index, wid) / lower_bound(index, wid+1)
//     (exactly 25 uniform iterations, top tree levels cache-resident; deep levels
//     L3-resident; latency hidden by ~390 waves/CU of streaming TLP)
//   - broadcast [beg,end) via shfl, then float4-vectorized coalesced sum of the
//     aligned body + scalar head/tail, wave butterfly reduce, lane 0 writes mean.
// HBM floor: x's 128 MB ~= 21 us. Index array is never streamed.

#define NSEG 100000

__global__ __launch_bounds__(256) void meanpool_fused(
    const float* __restrict__ x, const int* __restrict__ index, int n,
    float* __restrict__ out) {
    int wid  = (int)((blockIdx.x * (unsigned)blockDim.x + threadIdx.x) >> 6);
    int lane = threadIdx.x & 63;
    if (wid >= NSEG) return;

    // Lanes 0,1 search boundaries wid, wid+1. Trip count is uniform (~25):
    // hi-lo halves from n each iteration regardless of data.
    int bound = 0;
    if (lane < 2) {
        int target = wid + lane;   // for wid==NSEG-1, lane1 target==NSEG -> returns n
        int lo = 0, hi = n;
        while (lo < hi) {
            int mid = (lo + hi) >> 1;
            if (index[mid] < target) lo = mid + 1; else hi = mid;
        }
        bound = lo;
    }
    int beg = __shfl(bound, 0, 64);
    int end = __shfl(bound, 1, 64);

    float sum = 0.0f;
    int beg4 = (beg + 3) & ~3;   // first 16B-aligned element index
    int end4 = end & ~3;         // end of aligned body

    if (end4 <= beg4) {
        // Short segment: scalar.
        for (int i = beg + lane; i < end; i += 64) sum += x[i];
    } else {
        // Head: up to 3 scalars.
        if (lane < (beg4 - beg)) sum += x[beg + lane];
        // Body: float4, 16B/lane, fully coalesced (1 KiB per wave-instruction).
        for (int i = beg4 + lane * 4; i < end4; i += 64 * 4) {
            float4 v = *reinterpret_cast<const float4*>(x + i);
            sum += v.x + v.y + v.z + v.w;
        }
        // Tail: up to 3 scalars.
        if (lane < (end - end4)) sum += x[end4 + lane];
    }

    // Wave-64 butterfly reduce.
    #pragma unroll
    for (int off = 32; off > 0; off >>= 1) sum += __shfl_down(sum, off, 64);

    if (lane == 0) {
        int cnt = end - beg;
        out[wid] = sum / (float)(cnt > 0 ? cnt : 1);
    }
}

extern "C" void kernel_launch(void* const* d_in, const int* in_sizes, int n_in,
                              void* d_out, int out_size, void* d_ws, size_t ws_size,
                              hipStream_t stream) {
    const float* x   = (const float*)d_in[0];
    const int*   idx = (const int*)d_in[1];
    float*       out = (float*)d_out;
    int n = in_sizes[0];

    int threads = 256;                       // 4 waves/block
    int waves_per_block = threads / 64;
    int blocks = (NSEG + waves_per_block - 1) / waves_per_block;
    meanpool_fused<<<blocks, threads, 0, stream>>>(x, idx, n, out);
}

// Round 6
// 273.075 us; speedup vs baseline: 1.4306x; 1.4306x over previous
//
#include <hip/hip_runtime.h>

// MeanPooling: segment mean over sorted int32 segment ids.
//   N = 2^25 float32, NUM_SEGMENTS = 100000, index sorted ascending.
// Two-kernel design (r5 post-mortem: fusing the binary search into the
// streaming wave serialized 100K searches to 2 lanes/wave and put ~20K stall
// cycles on every wave's critical path -> 207us, latency-bound, VALUBusy 22%.
// Unfused r3 structure had both kernels < 77us combined < 154us.)
//   K1 bounds_kernel: one THREAD per boundary -> 64 lane-parallel searches per
//     wave, 1563 waves. ~25 lock-step gather iterations, top levels broadcast
//     L1-hit, deep levels L2/L3. Latency-bound ~10us.
//   K2 segsum_kernel: one wave per segment, boundaries from the 400KB ws table
//     (L1-broadcast), float4 coalesced body + scalar head/tail, butterfly
//     reduce. HBM-bound: ~128MB of x => ~21us floor at 6.3TB/s.

#define NSEG 100000

__global__ __launch_bounds__(256) void bounds_kernel(
    const int* __restrict__ index, int n, int* __restrict__ seg_start) {
    int s = blockIdx.x * blockDim.x + threadIdx.x;
    if (s > NSEG) return;
    // lower_bound: first i with index[i] >= s; s==NSEG yields n.
    int lo = 0, hi = n;
    while (lo < hi) {
        int mid = (lo + hi) >> 1;
        if (index[mid] < s) lo = mid + 1; else hi = mid;
    }
    seg_start[s] = lo;
}

__global__ __launch_bounds__(256) void segsum_kernel(
    const float* __restrict__ x, const int* __restrict__ seg_start,
    float* __restrict__ out) {
    int wid  = (int)((blockIdx.x * (unsigned)blockDim.x + threadIdx.x) >> 6);
    int lane = threadIdx.x & 63;
    if (wid >= NSEG) return;

    int beg = seg_start[wid];      // L1-broadcast (400KB table, hot)
    int end = seg_start[wid + 1];

    float sum = 0.0f;
    int beg4 = (beg + 3) & ~3;   // first 16B-aligned element index
    int end4 = end & ~3;         // end of aligned body

    if (end4 <= beg4) {
        // Short segment: scalar.
        for (int i = beg + lane; i < end; i += 64) sum += x[i];
    } else {
        // Head: up to 3 scalars.
        if (lane < (beg4 - beg)) sum += x[beg + lane];
        // Body: float4, 16B/lane, 1KiB per wave-instruction.
        for (int i = beg4 + lane * 4; i < end4; i += 64 * 4) {
            float4 v = *reinterpret_cast<const float4*>(x + i);
            sum += v.x + v.y + v.z + v.w;
        }
        // Tail: up to 3 scalars.
        if (lane < (end - end4)) sum += x[end4 + lane];
    }

    // Wave-64 butterfly reduce.
    #pragma unroll
    for (int off = 32; off > 0; off >>= 1) sum += __shfl_down(sum, off, 64);

    if (lane == 0) {
        int cnt = end - beg;
        out[wid] = sum / (float)(cnt > 0 ? cnt : 1);
    }
}

extern "C" void kernel_launch(void* const* d_in, const int* in_sizes, int n_in,
                              void* d_out, int out_size, void* d_ws, size_t ws_size,
                              hipStream_t stream) {
    const float* x   = (const float*)d_in[0];
    const int*   idx = (const int*)d_in[1];
    float*       out = (float*)d_out;
    int n = in_sizes[0];

    int* seg_start = (int*)d_ws;  // NSEG+1 ints = 400004 B of scratch

    {   // K1: boundaries via 64-lane-parallel binary search.
        int threads = 256;
        int blocks = (NSEG + 1 + threads - 1) / threads;
        bounds_kernel<<<blocks, threads, 0, stream>>>(idx, n, seg_start);
    }
    {   // K2: one wave per segment, float4 streaming sum + mean.
        int threads = 256;                       // 4 waves/block
        int waves_per_block = threads / 64;
        int blocks = (NSEG + waves_per_block - 1) / waves_per_block;
        segsum_kernel<<<blocks, threads, 0, stream>>>(x, seg_start, out);
    }
}